// Round 9
// baseline (153.115 us; speedup 1.0000x reference)
//
#include <hip/hip_runtime.h>
#include <hip/hip_bf16.h>

// ItemCodeDPQ: out[b,s, m*16+d] = (input_ids[b,s]==0) ? 0
//            : centroids[m, clamp(item_codes[input_ids[b,s], m], 0, 255), d]
// Shapes: input_ids (1024,200) int, item_codes (1e6,8) i32, centroids (8,256,16) f32
// Output: (1024,200,128) f32.
//
// R7: passed, absmax 0, headline 148.8 us; kernel itself < 63 us (absent from
// top-5 — harness fillBuffer poison dominates).
// R9: nontemporal stores via native clang vector type (HIP float4 is a class,
// rejected by the builtin). Output is write-once; nt streams it past L2 so the
// random item_codes gathers stay L2-resident.

#define PQ_M   8
#define VALS   256
#define SUB    16

typedef float f32x4 __attribute__((ext_vector_type(4)));

__global__ __launch_bounds__(256) void
dpq_kernel(const int* __restrict__ input_ids,
           const int* __restrict__ item_codes,
           const float* __restrict__ centroids,
           f32x4* __restrict__ out,
           int n_f4,        // total float4 elements of output = out_size/4
           int num_items)   // item_codes rows
{
    int t = blockIdx.x * blockDim.x + threadIdx.x;
    if (t >= n_f4) return;

    const int p = t >> 5;        // position index (b*S + s)
    const int q = t & 31;        // which float4 within the 128-float row

    const int id = input_ids[p]; // broadcast across the 32 lanes of a position

    f32x4 v = (f32x4)(0.f, 0.f, 0.f, 0.f);
    if (id != 0) {
        // clamp id for ADDRESSING only (id!=0 test above uses raw value)
        int idc = id;
        idc = idc < 0 ? 0 : (idc >= num_items ? num_items - 1 : idc);
        const int m = q >> 2;    // sub-codebook index 0..7
        int code = item_codes[idc * PQ_M + m];
        code = min(max(code, 0), VALS - 1);
        const f32x4* crow =
            (const f32x4*)(centroids + ((size_t)m * VALS + code) * SUB);
        v = crow[q & 3];
    }
    // Nontemporal: stream past L2 (write-once data) -> global_store_dwordx4 nt
    __builtin_nontemporal_store(v, &out[t]);
}

extern "C" void kernel_launch(void* const* d_in, const int* in_sizes, int n_in,
                              void* d_out, int out_size, void* d_ws, size_t ws_size,
                              hipStream_t stream)
{
    const int*   input_ids  = (const int*)d_in[0];
    const int*   item_codes = (const int*)d_in[1];
    const float* centroids  = (const float*)d_in[2];

    // Store bound from out_size (authoritative): out_size floats -> /4 float4s.
    const int n_f4      = out_size / 4;
    const int num_items = in_sizes[1] / PQ_M;   // 8e6 / 8 = 1e6

    const int block = 256;
    const int grid  = (n_f4 + block - 1) / block;
    dpq_kernel<<<grid, block, 0, stream>>>(input_ids, item_codes, centroids,
                                           (f32x4*)d_out, n_f4, num_items);
}

// Round 10
// 150.505 us; speedup vs baseline: 1.0173x; 1.0173x over previous
//
#include <hip/hip_runtime.h>
#include <hip/hip_bf16.h>

// ItemCodeDPQ: out[b,s, m*16+d] = (input_ids[b,s]==0) ? 0
//            : centroids[m, clamp(item_codes[input_ids[b,s], m], 0, 255), d]
// Shapes: input_ids (1024,200) int, item_codes (1e6,8) i32, centroids (8,256,16) f32
// Output: (1024,200,128) f32.
//
// R7 (this version): passed, absmax 0, headline 148.8 us. Kernel itself est.
// ~25 us (headline is ~115 us harness poison fills + ~11 us input restore);
// memory floor = 132 MB compulsory traffic / 6.3 TB/s = 21 us.
// R9 (nt stores): 153.1 us, but fills slowed 4% too -> nt neutral; reverted
// per rigor (unproven complication).

#define PQ_M   8
#define VALS   256
#define SUB    16

__global__ __launch_bounds__(256) void
dpq_kernel(const int* __restrict__ input_ids,
           const int* __restrict__ item_codes,
           const float* __restrict__ centroids,
           float4* __restrict__ out,
           int n_f4,        // total float4 elements of output = out_size/4
           int num_items)   // item_codes rows
{
    int t = blockIdx.x * blockDim.x + threadIdx.x;
    if (t >= n_f4) return;

    const int p = t >> 5;        // position index (b*S + s)
    const int q = t & 31;        // which float4 within the 128-float row

    const int id = input_ids[p]; // broadcast across the 32 lanes of a position

    float4 v = make_float4(0.f, 0.f, 0.f, 0.f);
    if (id != 0) {
        // clamp id for ADDRESSING only (id!=0 test above uses raw value)
        int idc = id;
        idc = idc < 0 ? 0 : (idc >= num_items ? num_items - 1 : idc);
        const int m = q >> 2;    // sub-codebook index 0..7
        int code = item_codes[idc * PQ_M + m];
        code = min(max(code, 0), VALS - 1);
        const float4* crow =
            (const float4*)(centroids + ((size_t)m * VALS + code) * SUB);
        v = crow[q & 3];
    }
    out[t] = v;
}

extern "C" void kernel_launch(void* const* d_in, const int* in_sizes, int n_in,
                              void* d_out, int out_size, void* d_ws, size_t ws_size,
                              hipStream_t stream)
{
    const int*   input_ids  = (const int*)d_in[0];
    const int*   item_codes = (const int*)d_in[1];
    const float* centroids  = (const float*)d_in[2];
    float*       out        = (float*)d_out;

    // Store bound from out_size (authoritative): out_size floats -> /4 float4s.
    const int n_f4      = out_size / 4;
    const int num_items = in_sizes[1] / PQ_M;   // 8e6 / 8 = 1e6

    const int block = 256;
    const int grid  = (n_f4 + block - 1) / block;
    dpq_kernel<<<grid, block, 0, stream>>>(input_ids, item_codes, centroids,
                                           (float4*)out, n_f4, num_items);
}